// Round 4
// baseline (824.076 us; speedup 1.0000x reference)
//
#include <hip/hip_runtime.h>

#define Bb 64
#define Nn 8192
#define Ff 32
#define Gg 32
#define G3 (Gg*Gg*Gg)

// One block per batch: centroid of 8192 coords, fp64 accumulation.
__global__ void __launch_bounds__(256) centers_kernel(const float* __restrict__ coords,
                                                      float* __restrict__ centers) {
    const int b = blockIdx.x;
    const int t = threadIdx.x;
    double sx = 0.0, sy = 0.0, sz = 0.0;
    const float* cb = coords + (size_t)b * Nn * 3;
    for (int n = t; n < Nn; n += 256) {
        sx += (double)cb[n * 3 + 0];
        sy += (double)cb[n * 3 + 1];
        sz += (double)cb[n * 3 + 2];
    }
    __shared__ double red[256][3];
    red[t][0] = sx; red[t][1] = sy; red[t][2] = sz;
    __syncthreads();
    for (int s = 128; s > 0; s >>= 1) {
        if (t < s) {
            red[t][0] += red[t + s][0];
            red[t][1] += red[t + s][1];
            red[t][2] += red[t + s][2];
        }
        __syncthreads();
    }
    if (t < 3) centers[b * 3 + t] = (float)(red[0][t] * (1.0 / Nn));
}

// Thread per atom: linear (W in LDS, broadcast reads) -> voxel idx -> 32 atomicAdds.
__global__ void __launch_bounds__(256) scatter_kernel(const float* __restrict__ coords,
                                                      const float* __restrict__ features,
                                                      const float* __restrict__ W,
                                                      const float* __restrict__ bias,
                                                      const float* __restrict__ centers,
                                                      float* __restrict__ out) {
    __shared__ float Wl[Ff * Ff];
    __shared__ float bl[Ff];
    for (int i = threadIdx.x; i < Ff * Ff; i += 256) Wl[i] = W[i];
    if (threadIdx.x < Ff) bl[threadIdx.x] = bias[threadIdx.x];
    __syncthreads();

    const int atom = blockIdx.x * 256 + threadIdx.x;  // 0 .. B*N-1
    const int b = atom >> 13;                         // atom / N

    // centroid for this batch (same address for half the wave -> cached/broadcast)
    const float cx = centers[b * 3 + 0];
    const float cy = centers[b * 3 + 1];
    const float cz = centers[b * 3 + 2];

    const float* cp = coords + (size_t)atom * 3;
    const float sxf = (cp[0] - cx) + 16.0f;   // (c - center)/VOXEL_SIZE + G/2, VOXEL_SIZE=1
    const float syf = (cp[1] - cy) + 16.0f;
    const float szf = (cp[2] - cz) + 16.0f;
    // trunc-toward-zero like .astype(int32), then clip to [0, G-1]
    const int ix = min(max((int)sxf, 0), Gg - 1);
    const int iy = min(max((int)syf, 0), Gg - 1);
    const int iz = min(max((int)szf, 0), Gg - 1);
    const int spatial = ix * (Gg * Gg) + iy * Gg + iz;
    float* outb = out + (size_t)b * Ff * G3 + spatial;

    // load the atom's 32 features (8 x float4)
    float ft[Ff];
    const float4* f4 = reinterpret_cast<const float4*>(features + (size_t)atom * Ff);
    #pragma unroll
    for (int k = 0; k < 8; ++k) {
        const float4 v = f4[k];
        ft[4 * k + 0] = v.x; ft[4 * k + 1] = v.y;
        ft[4 * k + 2] = v.z; ft[4 * k + 3] = v.w;
    }

    // feats[fo] = b[fo] + sum_j features[j] * W[fo][j]  (= features @ W.T + b)
    #pragma unroll 4
    for (int fo = 0; fo < Ff; ++fo) {
        float acc = bl[fo];
        #pragma unroll
        for (int j = 0; j < Ff; ++j) acc += Wl[fo * Ff + j] * ft[j];
        atomicAdd(outb + (size_t)fo * G3, acc);
    }
}

extern "C" void kernel_launch(void* const* d_in, const int* in_sizes, int n_in,
                              void* d_out, int out_size, void* d_ws, size_t ws_size,
                              hipStream_t stream) {
    const float* coords   = (const float*)d_in[0];
    const float* features = (const float*)d_in[1];
    const float* W        = (const float*)d_in[2];
    const float* bias     = (const float*)d_in[3];
    float* out = (float*)d_out;
    float* centers = (float*)d_ws;  // 64*3 floats of scratch

    hipMemsetAsync(d_out, 0, (size_t)out_size * sizeof(float), stream);
    centers_kernel<<<Bb, 256, 0, stream>>>(coords, centers);
    scatter_kernel<<<(Bb * Nn) / 256, 256, 0, stream>>>(coords, features, W, bias, centers, out);
}

// Round 5
// 235.687 us; speedup vs baseline: 3.4965x; 3.4965x over previous
//
#include <hip/hip_runtime.h>

#define Bb 64
#define Nn 8192
#define Ff 32
#define Gg 32
#define G3 (Gg*Gg*Gg)          // 32768
#define NATOM (Bb*Nn)          // 524288
#define NBINS (Bb*G3)          // 2^21
#define SCAN_BLK 1024          // blocks in scan pass1/3 (2048 items each)

// ---------------- ws layout ----------------
// [0,1024)              centers (64*3 f32)
// [1024, +8MB)          cnt[NBINS]      (u32)
// [+8MB,  +8MB)         off[NBINS]      (u32)  exclusive offsets; destroyed by place
// [+2MB)                vox[NATOM]      (u32)
// [+2MB)                atomIdx[NATOM]  (u32)
// [+4KB)                blockSums[SCAN_BLK]
static const size_t WS_CENTERS = 0;
static const size_t WS_CNT     = 1024;
static const size_t WS_OFF     = WS_CNT + (size_t)NBINS * 4;
static const size_t WS_VOX     = WS_OFF + (size_t)NBINS * 4;
static const size_t WS_AIDX    = WS_VOX + (size_t)NATOM * 4;
static const size_t WS_BSUM    = WS_AIDX + (size_t)NATOM * 4;
static const size_t WS_NEED    = WS_BSUM + (size_t)SCAN_BLK * 4;

// One block per batch: centroid of 8192 coords, fp64 accumulation.
__global__ void __launch_bounds__(256) centers_kernel(const float* __restrict__ coords,
                                                      float* __restrict__ centers) {
    const int b = blockIdx.x;
    const int t = threadIdx.x;
    double sx = 0.0, sy = 0.0, sz = 0.0;
    const float* cb = coords + (size_t)b * Nn * 3;
    for (int n = t; n < Nn; n += 256) {
        sx += (double)cb[n * 3 + 0];
        sy += (double)cb[n * 3 + 1];
        sz += (double)cb[n * 3 + 2];
    }
    __shared__ double red[256][3];
    red[t][0] = sx; red[t][1] = sy; red[t][2] = sz;
    __syncthreads();
    for (int s = 128; s > 0; s >>= 1) {
        if (t < s) {
            red[t][0] += red[t + s][0];
            red[t][1] += red[t + s][1];
            red[t][2] += red[t + s][2];
        }
        __syncthreads();
    }
    if (t < 3) centers[b * 3 + t] = (float)(red[0][t] * (1.0 / Nn));
}

// Per atom: voxel bin id + count histogram.
__global__ void __launch_bounds__(256) binid_kernel(const float* __restrict__ coords,
                                                    const float* __restrict__ centers,
                                                    unsigned* __restrict__ vox,
                                                    unsigned* __restrict__ cnt) {
    const int atom = blockIdx.x * 256 + threadIdx.x;
    const int b = atom >> 13;
    const float cx = centers[b * 3 + 0];
    const float cy = centers[b * 3 + 1];
    const float cz = centers[b * 3 + 2];
    const float* cp = coords + (size_t)atom * 3;
    const int ix = min(max((int)((cp[0] - cx) + 16.0f), 0), Gg - 1);
    const int iy = min(max((int)((cp[1] - cy) + 16.0f), 0), Gg - 1);
    const int iz = min(max((int)((cp[2] - cz) + 16.0f), 0), Gg - 1);
    const unsigned bin = ((unsigned)b << 15) | ((unsigned)ix << 10) | ((unsigned)iy << 5) | (unsigned)iz;
    vox[atom] = bin;
    atomicAdd(&cnt[bin], 1u);
}

// Scan pass 1: per-block (2048 items) totals.
__global__ void __launch_bounds__(256) scan_pass1(const unsigned* __restrict__ cnt,
                                                  unsigned* __restrict__ bsum) {
    __shared__ unsigned red[256];
    const int t = threadIdx.x;
    const size_t base = (size_t)blockIdx.x * 2048 + (size_t)t * 8;
    unsigned s = 0;
    #pragma unroll
    for (int i = 0; i < 8; ++i) s += cnt[base + i];
    red[t] = s;
    __syncthreads();
    for (int d = 128; d > 0; d >>= 1) {
        if (t < d) red[t] += red[t + d];
        __syncthreads();
    }
    if (t == 0) bsum[blockIdx.x] = red[0];
}

// Scan pass 2: single block exclusive-scans blockSums (SCAN_BLK=1024 elems, 4/thread).
__global__ void __launch_bounds__(256) scan_pass2(unsigned* __restrict__ bsum) {
    __shared__ unsigned tt[256];
    const int t = threadIdx.x;
    unsigned v[4];
    unsigned s = 0;
    #pragma unroll
    for (int i = 0; i < 4; ++i) { v[i] = bsum[t * 4 + i]; s += v[i]; }
    tt[t] = s;
    __syncthreads();
    for (int d = 1; d < 256; d <<= 1) {
        unsigned y = 0;
        if (t >= d) y = tt[t - d];
        __syncthreads();
        if (t >= d) tt[t] += y;
        __syncthreads();
    }
    unsigned run = (t > 0) ? tt[t - 1] : 0u;
    #pragma unroll
    for (int i = 0; i < 4; ++i) { unsigned c = v[i]; bsum[t * 4 + i] = run; run += c; }
}

// Scan pass 3: ordered exclusive scan within each 2048 chunk + block prefix -> off[].
__global__ void __launch_bounds__(256) scan_pass3(const unsigned* __restrict__ cnt,
                                                  const unsigned* __restrict__ bsum,
                                                  unsigned* __restrict__ off) {
    __shared__ unsigned tt[256];
    const int t = threadIdx.x;
    const size_t base = (size_t)blockIdx.x * 2048 + (size_t)t * 8;
    unsigned v[8];
    unsigned s = 0;
    #pragma unroll
    for (int i = 0; i < 8; ++i) { v[i] = cnt[base + i]; s += v[i]; }
    tt[t] = s;
    __syncthreads();
    for (int d = 1; d < 256; d <<= 1) {
        unsigned y = 0;
        if (t >= d) y = tt[t - d];
        __syncthreads();
        if (t >= d) tt[t] += y;
        __syncthreads();
    }
    unsigned run = bsum[blockIdx.x] + ((t > 0) ? tt[t - 1] : 0u);
    #pragma unroll
    for (int i = 0; i < 8; ++i) { off[base + i] = run; run += v[i]; }
}

// Place atoms into bin-sorted order. Destroys off[] (becomes end pointers).
__global__ void __launch_bounds__(256) place_kernel(const unsigned* __restrict__ vox,
                                                    unsigned* __restrict__ off,
                                                    unsigned* __restrict__ atomIdx) {
    const int atom = blockIdx.x * 256 + threadIdx.x;
    const unsigned bin = vox[atom];
    const unsigned pos = atomicAdd(&off[bin], 1u);
    atomIdx[pos] = atom;
}

// One thread per output cell: sum raw features of its atoms, apply linear per-cell,
// write all 32 f-planes coalesced. off[] holds END pointers after place: start=end-k.
__global__ void __launch_bounds__(256) gather_kernel(const unsigned* __restrict__ cnt,
                                                     const unsigned* __restrict__ off_end,
                                                     const unsigned* __restrict__ atomIdx,
                                                     const float* __restrict__ features,
                                                     const float* __restrict__ W,
                                                     const float* __restrict__ bias,
                                                     float* __restrict__ out) {
    __shared__ float Wl[Ff * Ff];
    __shared__ float bl[Ff];
    for (int i = threadIdx.x; i < Ff * Ff; i += 256) Wl[i] = W[i];
    if (threadIdx.x < Ff) bl[threadIdx.x] = bias[threadIdx.x];
    __syncthreads();

    const int b = blockIdx.x >> 7;                 // 128 chunks of 256 cells per batch
    const int spatial = ((blockIdx.x & 127) << 8) + threadIdx.x;
    const unsigned bin = ((unsigned)b << 15) + (unsigned)spatial;
    const unsigned k = cnt[bin];
    const unsigned start = off_end[bin] - k;

    float acc[Ff];
    #pragma unroll
    for (int j = 0; j < Ff; ++j) acc[j] = 0.0f;
    for (unsigned i = 0; i < k; ++i) {
        const unsigned a = atomIdx[start + i];
        const float4* f4 = reinterpret_cast<const float4*>(features + (size_t)a * Ff);
        #pragma unroll
        for (int q = 0; q < 8; ++q) {
            const float4 v = f4[q];
            acc[4 * q + 0] += v.x; acc[4 * q + 1] += v.y;
            acc[4 * q + 2] += v.z; acc[4 * q + 3] += v.w;
        }
    }

    float* outb = out + (size_t)b * Ff * G3 + spatial;
    const float fk = (float)k;
    #pragma unroll 4
    for (int f = 0; f < Ff; ++f) {
        float val = fk * bl[f];
        #pragma unroll
        for (int j = 0; j < Ff; ++j) val += Wl[f * Ff + j] * acc[j];
        outb[(size_t)f * G3] = val;    // consecutive threads -> consecutive addresses
    }
}

// ---------- fallback (old atomic path) if ws is too small ----------
__global__ void __launch_bounds__(256) scatter_kernel(const float* __restrict__ coords,
                                                      const float* __restrict__ features,
                                                      const float* __restrict__ W,
                                                      const float* __restrict__ bias,
                                                      const float* __restrict__ centers,
                                                      float* __restrict__ out) {
    __shared__ float Wl[Ff * Ff];
    __shared__ float bl[Ff];
    for (int i = threadIdx.x; i < Ff * Ff; i += 256) Wl[i] = W[i];
    if (threadIdx.x < Ff) bl[threadIdx.x] = bias[threadIdx.x];
    __syncthreads();
    const int atom = blockIdx.x * 256 + threadIdx.x;
    const int b = atom >> 13;
    const float cx = centers[b * 3 + 0];
    const float cy = centers[b * 3 + 1];
    const float cz = centers[b * 3 + 2];
    const float* cp = coords + (size_t)atom * 3;
    const int ix = min(max((int)((cp[0] - cx) + 16.0f), 0), Gg - 1);
    const int iy = min(max((int)((cp[1] - cy) + 16.0f), 0), Gg - 1);
    const int iz = min(max((int)((cp[2] - cz) + 16.0f), 0), Gg - 1);
    const int spatial = ix * (Gg * Gg) + iy * Gg + iz;
    float* outb = out + (size_t)b * Ff * G3 + spatial;
    float ft[Ff];
    const float4* f4 = reinterpret_cast<const float4*>(features + (size_t)atom * Ff);
    #pragma unroll
    for (int q = 0; q < 8; ++q) {
        const float4 v = f4[q];
        ft[4 * q + 0] = v.x; ft[4 * q + 1] = v.y;
        ft[4 * q + 2] = v.z; ft[4 * q + 3] = v.w;
    }
    #pragma unroll 4
    for (int fo = 0; fo < Ff; ++fo) {
        float a2 = bl[fo];
        #pragma unroll
        for (int j = 0; j < Ff; ++j) a2 += Wl[fo * Ff + j] * ft[j];
        atomicAdd(outb + (size_t)fo * G3, a2);
    }
}

extern "C" void kernel_launch(void* const* d_in, const int* in_sizes, int n_in,
                              void* d_out, int out_size, void* d_ws, size_t ws_size,
                              hipStream_t stream) {
    const float* coords   = (const float*)d_in[0];
    const float* features = (const float*)d_in[1];
    const float* W        = (const float*)d_in[2];
    const float* bias     = (const float*)d_in[3];
    float* out = (float*)d_out;

    char* ws = (char*)d_ws;
    float*    centers = (float*)(ws + WS_CENTERS);

    if (ws_size < WS_NEED) {
        // fallback: original atomic path
        hipMemsetAsync(d_out, 0, (size_t)out_size * sizeof(float), stream);
        centers_kernel<<<Bb, 256, 0, stream>>>(coords, centers);
        scatter_kernel<<<(NATOM) / 256, 256, 0, stream>>>(coords, features, W, bias, centers, out);
        return;
    }

    unsigned* cnt     = (unsigned*)(ws + WS_CNT);
    unsigned* off     = (unsigned*)(ws + WS_OFF);
    unsigned* vox     = (unsigned*)(ws + WS_VOX);
    unsigned* atomIdx = (unsigned*)(ws + WS_AIDX);
    unsigned* bsum    = (unsigned*)(ws + WS_BSUM);

    hipMemsetAsync(cnt, 0, (size_t)NBINS * 4, stream);
    centers_kernel<<<Bb, 256, 0, stream>>>(coords, centers);
    binid_kernel<<<NATOM / 256, 256, 0, stream>>>(coords, centers, vox, cnt);
    scan_pass1<<<SCAN_BLK, 256, 0, stream>>>(cnt, bsum);
    scan_pass2<<<1, 256, 0, stream>>>(bsum);
    scan_pass3<<<SCAN_BLK, 256, 0, stream>>>(cnt, bsum, off);
    place_kernel<<<NATOM / 256, 256, 0, stream>>>(vox, off, atomIdx);
    gather_kernel<<<Bb * (G3 / 256), 256, 0, stream>>>(cnt, off, atomIdx, features, W, bias, out);
}

// Round 7
// 199.944 us; speedup vs baseline: 4.1215x; 1.1788x over previous
//
#include <hip/hip_runtime.h>

#define Bb 64
#define Nn 8192
#define Ff 32
#define Gg 32
#define G3 (Gg*Gg*Gg)          // 32768
#define NATOM (Bb*Nn)          // 524288
#define NBINS (Bb*G3)          // 2^21
#define SCAN_BLK 1024          // blocks in scan pass1/3 (2048 items each)

// ---------------- ws layout ----------------
static const size_t WS_CENTERS = 0;
static const size_t WS_CNT     = 1024;
static const size_t WS_OFF     = WS_CNT + (size_t)NBINS * 4;
static const size_t WS_VOX     = WS_OFF + (size_t)NBINS * 4;
static const size_t WS_AIDX    = WS_VOX + (size_t)NATOM * 4;
static const size_t WS_BSUM    = WS_AIDX + (size_t)NATOM * 4;
static const size_t WS_NEED    = WS_BSUM + (size_t)SCAN_BLK * 4;

// One block per batch: centroid of 8192 coords, fp64 accumulation.
__global__ void __launch_bounds__(256) centers_kernel(const float* __restrict__ coords,
                                                      float* __restrict__ centers) {
    const int b = blockIdx.x;
    const int t = threadIdx.x;
    double sx = 0.0, sy = 0.0, sz = 0.0;
    const float* cb = coords + (size_t)b * Nn * 3;
    for (int n = t; n < Nn; n += 256) {
        sx += (double)cb[n * 3 + 0];
        sy += (double)cb[n * 3 + 1];
        sz += (double)cb[n * 3 + 2];
    }
    __shared__ double red[256][3];
    red[t][0] = sx; red[t][1] = sy; red[t][2] = sz;
    __syncthreads();
    for (int s = 128; s > 0; s >>= 1) {
        if (t < s) {
            red[t][0] += red[t + s][0];
            red[t][1] += red[t + s][1];
            red[t][2] += red[t + s][2];
        }
        __syncthreads();
    }
    if (t < 3) centers[b * 3 + t] = (float)(red[0][t] * (1.0 / Nn));
}

// Per atom: voxel bin id + count histogram.
__global__ void __launch_bounds__(256) binid_kernel(const float* __restrict__ coords,
                                                    const float* __restrict__ centers,
                                                    unsigned* __restrict__ vox,
                                                    unsigned* __restrict__ cnt) {
    const int atom = blockIdx.x * 256 + threadIdx.x;
    const int b = atom >> 13;
    const float cx = centers[b * 3 + 0];
    const float cy = centers[b * 3 + 1];
    const float cz = centers[b * 3 + 2];
    const float* cp = coords + (size_t)atom * 3;
    const int ix = min(max((int)((cp[0] - cx) + 16.0f), 0), Gg - 1);
    const int iy = min(max((int)((cp[1] - cy) + 16.0f), 0), Gg - 1);
    const int iz = min(max((int)((cp[2] - cz) + 16.0f), 0), Gg - 1);
    const unsigned bin = ((unsigned)b << 15) | ((unsigned)ix << 10) | ((unsigned)iy << 5) | (unsigned)iz;
    vox[atom] = bin;
    atomicAdd(&cnt[bin], 1u);
}

// Scan pass 1: per-block (2048 items) totals.
__global__ void __launch_bounds__(256) scan_pass1(const unsigned* __restrict__ cnt,
                                                  unsigned* __restrict__ bsum) {
    __shared__ unsigned red[256];
    const int t = threadIdx.x;
    const size_t base = (size_t)blockIdx.x * 2048 + (size_t)t * 8;
    unsigned s = 0;
    #pragma unroll
    for (int i = 0; i < 8; ++i) s += cnt[base + i];
    red[t] = s;
    __syncthreads();
    for (int d = 128; d > 0; d >>= 1) {
        if (t < d) red[t] += red[t + d];
        __syncthreads();
    }
    if (t == 0) bsum[blockIdx.x] = red[0];
}

// Scan pass 2: single block exclusive-scans blockSums (SCAN_BLK=1024 elems, 4/thread).
__global__ void __launch_bounds__(256) scan_pass2(unsigned* __restrict__ bsum) {
    __shared__ unsigned tt[256];
    const int t = threadIdx.x;
    unsigned v[4];
    unsigned s = 0;
    #pragma unroll
    for (int i = 0; i < 4; ++i) { v[i] = bsum[t * 4 + i]; s += v[i]; }
    tt[t] = s;
    __syncthreads();
    for (int d = 1; d < 256; d <<= 1) {
        unsigned y = 0;
        if (t >= d) y = tt[t - d];
        __syncthreads();
        if (t >= d) tt[t] += y;
        __syncthreads();
    }
    unsigned run = (t > 0) ? tt[t - 1] : 0u;
    #pragma unroll
    for (int i = 0; i < 4; ++i) { unsigned c = v[i]; bsum[t * 4 + i] = run; run += c; }
}

// Scan pass 3: ordered exclusive scan within each 2048 chunk + block prefix -> off[].
__global__ void __launch_bounds__(256) scan_pass3(const unsigned* __restrict__ cnt,
                                                  const unsigned* __restrict__ bsum,
                                                  unsigned* __restrict__ off) {
    __shared__ unsigned tt[256];
    const int t = threadIdx.x;
    const size_t base = (size_t)blockIdx.x * 2048 + (size_t)t * 8;
    unsigned v[8];
    unsigned s = 0;
    #pragma unroll
    for (int i = 0; i < 8; ++i) { v[i] = cnt[base + i]; s += v[i]; }
    tt[t] = s;
    __syncthreads();
    for (int d = 1; d < 256; d <<= 1) {
        unsigned y = 0;
        if (t >= d) y = tt[t - d];
        __syncthreads();
        if (t >= d) tt[t] += y;
        __syncthreads();
    }
    unsigned run = bsum[blockIdx.x] + ((t > 0) ? tt[t - 1] : 0u);
    #pragma unroll
    for (int i = 0; i < 8; ++i) { off[base + i] = run; run += v[i]; }
}

// Place atoms into bin-sorted order. Destroys off[] (becomes end pointers).
__global__ void __launch_bounds__(256) place_kernel(const unsigned* __restrict__ vox,
                                                    unsigned* __restrict__ off,
                                                    unsigned* __restrict__ atomIdx) {
    const int atom = blockIdx.x * 256 + threadIdx.x;
    const unsigned bin = vox[atom];
    const unsigned pos = atomicAdd(&off[bin], 1u);
    atomIdx[pos] = atom;
}

// One thread per output cell. W/bias read via wave-uniform scalar loads (SGPR,
// K$-cached) -> matvec is pure v_fmac, no LDS pipe. Empty waves write zeros
// and exit (wave-uniform branch, no divergence cost).
__global__ void __launch_bounds__(256) gather_kernel(const unsigned* __restrict__ cnt,
                                                     const unsigned* __restrict__ off_end,
                                                     const unsigned* __restrict__ atomIdx,
                                                     const float* __restrict__ features,
                                                     const float* __restrict__ W,
                                                     const float* __restrict__ bias,
                                                     float* __restrict__ out) {
    const int b = blockIdx.x >> 7;                 // 128 chunks of 256 cells per batch
    const int spatial = ((blockIdx.x & 127) << 8) + threadIdx.x;
    const unsigned bin = ((unsigned)b << 15) + (unsigned)spatial;
    const unsigned k = cnt[bin];
    float* outb = out + (size_t)b * Ff * G3 + spatial;

    if (!__any((int)k)) {                          // whole wave empty: zero-fill, done
        #pragma unroll
        for (int f = 0; f < Ff; ++f) outb[(size_t)f * G3] = 0.0f;
        return;
    }

    const unsigned start = off_end[bin] - k;
    float acc[Ff];
    #pragma unroll
    for (int j = 0; j < Ff; ++j) acc[j] = 0.0f;
    for (unsigned i = 0; i < k; ++i) {
        const unsigned a = atomIdx[start + i];
        const float4* f4 = reinterpret_cast<const float4*>(features + (size_t)a * Ff);
        #pragma unroll
        for (int q = 0; q < 8; ++q) {
            const float4 v = f4[q];
            acc[4 * q + 0] += v.x; acc[4 * q + 1] += v.y;
            acc[4 * q + 2] += v.z; acc[4 * q + 3] += v.w;
        }
    }

    const float fk = (float)k;
    #pragma unroll
    for (int f = 0; f < Ff; f += 4) {              // 4 independent FMA chains
        float v0 = fk * bias[f + 0];
        float v1 = fk * bias[f + 1];
        float v2 = fk * bias[f + 2];
        float v3 = fk * bias[f + 3];
        #pragma unroll
        for (int j = 0; j < Ff; ++j) {
            const float a = acc[j];
            v0 += W[(f + 0) * Ff + j] * a;         // uniform idx -> s_load, v_fmac v,s,v
            v1 += W[(f + 1) * Ff + j] * a;
            v2 += W[(f + 2) * Ff + j] * a;
            v3 += W[(f + 3) * Ff + j] * a;
        }
        outb[(size_t)(f + 0) * G3] = v0;
        outb[(size_t)(f + 1) * G3] = v1;
        outb[(size_t)(f + 2) * G3] = v2;
        outb[(size_t)(f + 3) * G3] = v3;
    }
}

// ---------- fallback (old atomic path) if ws is too small ----------
__global__ void __launch_bounds__(256) scatter_kernel(const float* __restrict__ coords,
                                                      const float* __restrict__ features,
                                                      const float* __restrict__ W,
                                                      const float* __restrict__ bias,
                                                      const float* __restrict__ centers,
                                                      float* __restrict__ out) {
    __shared__ float Wl[Ff * Ff];
    __shared__ float bl[Ff];
    for (int i = threadIdx.x; i < Ff * Ff; i += 256) Wl[i] = W[i];
    if (threadIdx.x < Ff) bl[threadIdx.x] = bias[threadIdx.x];
    __syncthreads();
    const int atom = blockIdx.x * 256 + threadIdx.x;
    const int b = atom >> 13;
    const float cx = centers[b * 3 + 0];
    const float cy = centers[b * 3 + 1];
    const float cz = centers[b * 3 + 2];
    const float* cp = coords + (size_t)atom * 3;
    const int ix = min(max((int)((cp[0] - cx) + 16.0f), 0), Gg - 1);
    const int iy = min(max((int)((cp[1] - cy) + 16.0f), 0), Gg - 1);
    const int iz = min(max((int)((cp[2] - cz) + 16.0f), 0), Gg - 1);
    const int spatial = ix * (Gg * Gg) + iy * Gg + iz;
    float* outb = out + (size_t)b * Ff * G3 + spatial;
    float ft[Ff];
    const float4* f4 = reinterpret_cast<const float4*>(features + (size_t)atom * Ff);
    #pragma unroll
    for (int q = 0; q < 8; ++q) {
        const float4 v = f4[q];
        ft[4 * q + 0] = v.x; ft[4 * q + 1] = v.y;
        ft[4 * q + 2] = v.z; ft[4 * q + 3] = v.w;
    }
    #pragma unroll 4
    for (int fo = 0; fo < Ff; ++fo) {
        float a2 = bl[fo];
        #pragma unroll
        for (int j = 0; j < Ff; ++j) a2 += Wl[fo * Ff + j] * ft[j];
        atomicAdd(outb + (size_t)fo * G3, a2);
    }
}

extern "C" void kernel_launch(void* const* d_in, const int* in_sizes, int n_in,
                              void* d_out, int out_size, void* d_ws, size_t ws_size,
                              hipStream_t stream) {
    const float* coords   = (const float*)d_in[0];
    const float* features = (const float*)d_in[1];
    const float* W        = (const float*)d_in[2];
    const float* bias     = (const float*)d_in[3];
    float* out = (float*)d_out;

    char* ws = (char*)d_ws;
    float* centers = (float*)(ws + WS_CENTERS);

    if (ws_size < WS_NEED) {
        hipMemsetAsync(d_out, 0, (size_t)out_size * sizeof(float), stream);
        centers_kernel<<<Bb, 256, 0, stream>>>(coords, centers);
        scatter_kernel<<<(NATOM) / 256, 256, 0, stream>>>(coords, features, W, bias, centers, out);
        return;
    }

    unsigned* cnt     = (unsigned*)(ws + WS_CNT);
    unsigned* off     = (unsigned*)(ws + WS_OFF);
    unsigned* vox     = (unsigned*)(ws + WS_VOX);
    unsigned* atomIdx = (unsigned*)(ws + WS_AIDX);
    unsigned* bsum    = (unsigned*)(ws + WS_BSUM);

    hipMemsetAsync(cnt, 0, (size_t)NBINS * 4, stream);
    centers_kernel<<<Bb, 256, 0, stream>>>(coords, centers);
    binid_kernel<<<NATOM / 256, 256, 0, stream>>>(coords, centers, vox, cnt);
    scan_pass1<<<SCAN_BLK, 256, 0, stream>>>(cnt, bsum);
    scan_pass2<<<1, 256, 0, stream>>>(bsum);
    scan_pass3<<<SCAN_BLK, 256, 0, stream>>>(cnt, bsum, off);
    place_kernel<<<NATOM / 256, 256, 0, stream>>>(vox, off, atomIdx);
    gather_kernel<<<Bb * (G3 / 256), 256, 0, stream>>>(cnt, off, atomIdx, features, W, bias, out);
}

// Round 8
// 196.387 us; speedup vs baseline: 4.1962x; 1.0181x over previous
//
#include <hip/hip_runtime.h>

#define Bb 64
#define Nn 8192
#define Ff 32
#define Gg 32
#define G3 (Gg*Gg*Gg)          // 32768
#define NATOM (Bb*Nn)          // 524288
#define NBINS (Bb*G3)          // 2^21
#define SCAN_BLK 1024          // blocks in scan pass1/3 (2048 items each)

// ---------------- ws layout ----------------
static const size_t WS_CENTERS = 0;
static const size_t WS_CNT     = 1024;
static const size_t WS_OFF     = WS_CNT + (size_t)NBINS * 4;
static const size_t WS_VOX     = WS_OFF + (size_t)NBINS * 4;
static const size_t WS_AIDX    = WS_VOX + (size_t)NATOM * 4;
static const size_t WS_BSUM    = WS_AIDX + (size_t)NATOM * 4;
static const size_t WS_NEED    = WS_BSUM + (size_t)SCAN_BLK * 4;

// Grid-saturating uint4 zero fill: 2048 blocks x 256 threads x 16B = 8 MB.
// Replaces hipMemsetAsync's rocclr fill kernel (measured 153 us @ 52 GB/s
// effective -- tiny grid, scalar stores). This is one coalesced wave-store
// per thread.
__global__ void __launch_bounds__(256) zero_cnt_kernel(uint4* __restrict__ p) {
    const unsigned i = blockIdx.x * 256 + threadIdx.x;
    p[i] = make_uint4(0u, 0u, 0u, 0u);
}

// One block per batch: centroid of 8192 coords, fp64 accumulation.
__global__ void __launch_bounds__(256) centers_kernel(const float* __restrict__ coords,
                                                      float* __restrict__ centers) {
    const int b = blockIdx.x;
    const int t = threadIdx.x;
    double sx = 0.0, sy = 0.0, sz = 0.0;
    const float* cb = coords + (size_t)b * Nn * 3;
    for (int n = t; n < Nn; n += 256) {
        sx += (double)cb[n * 3 + 0];
        sy += (double)cb[n * 3 + 1];
        sz += (double)cb[n * 3 + 2];
    }
    __shared__ double red[256][3];
    red[t][0] = sx; red[t][1] = sy; red[t][2] = sz;
    __syncthreads();
    for (int s = 128; s > 0; s >>= 1) {
        if (t < s) {
            red[t][0] += red[t + s][0];
            red[t][1] += red[t + s][1];
            red[t][2] += red[t + s][2];
        }
        __syncthreads();
    }
    if (t < 3) centers[b * 3 + t] = (float)(red[0][t] * (1.0 / Nn));
}

// Per atom: voxel bin id + count histogram.
__global__ void __launch_bounds__(256) binid_kernel(const float* __restrict__ coords,
                                                    const float* __restrict__ centers,
                                                    unsigned* __restrict__ vox,
                                                    unsigned* __restrict__ cnt) {
    const int atom = blockIdx.x * 256 + threadIdx.x;
    const int b = atom >> 13;
    const float cx = centers[b * 3 + 0];
    const float cy = centers[b * 3 + 1];
    const float cz = centers[b * 3 + 2];
    const float* cp = coords + (size_t)atom * 3;
    const int ix = min(max((int)((cp[0] - cx) + 16.0f), 0), Gg - 1);
    const int iy = min(max((int)((cp[1] - cy) + 16.0f), 0), Gg - 1);
    const int iz = min(max((int)((cp[2] - cz) + 16.0f), 0), Gg - 1);
    const unsigned bin = ((unsigned)b << 15) | ((unsigned)ix << 10) | ((unsigned)iy << 5) | (unsigned)iz;
    vox[atom] = bin;
    atomicAdd(&cnt[bin], 1u);
}

// Scan pass 1: per-block (2048 items) totals.
__global__ void __launch_bounds__(256) scan_pass1(const unsigned* __restrict__ cnt,
                                                  unsigned* __restrict__ bsum) {
    __shared__ unsigned red[256];
    const int t = threadIdx.x;
    const size_t base = (size_t)blockIdx.x * 2048 + (size_t)t * 8;
    unsigned s = 0;
    #pragma unroll
    for (int i = 0; i < 8; ++i) s += cnt[base + i];
    red[t] = s;
    __syncthreads();
    for (int d = 128; d > 0; d >>= 1) {
        if (t < d) red[t] += red[t + d];
        __syncthreads();
    }
    if (t == 0) bsum[blockIdx.x] = red[0];
}

// Scan pass 2: single block exclusive-scans blockSums (SCAN_BLK=1024 elems, 4/thread).
__global__ void __launch_bounds__(256) scan_pass2(unsigned* __restrict__ bsum) {
    __shared__ unsigned tt[256];
    const int t = threadIdx.x;
    unsigned v[4];
    unsigned s = 0;
    #pragma unroll
    for (int i = 0; i < 4; ++i) { v[i] = bsum[t * 4 + i]; s += v[i]; }
    tt[t] = s;
    __syncthreads();
    for (int d = 1; d < 256; d <<= 1) {
        unsigned y = 0;
        if (t >= d) y = tt[t - d];
        __syncthreads();
        if (t >= d) tt[t] += y;
        __syncthreads();
    }
    unsigned run = (t > 0) ? tt[t - 1] : 0u;
    #pragma unroll
    for (int i = 0; i < 4; ++i) { unsigned c = v[i]; bsum[t * 4 + i] = run; run += c; }
}

// Scan pass 3: ordered exclusive scan within each 2048 chunk + block prefix -> off[].
__global__ void __launch_bounds__(256) scan_pass3(const unsigned* __restrict__ cnt,
                                                  const unsigned* __restrict__ bsum,
                                                  unsigned* __restrict__ off) {
    __shared__ unsigned tt[256];
    const int t = threadIdx.x;
    const size_t base = (size_t)blockIdx.x * 2048 + (size_t)t * 8;
    unsigned v[8];
    unsigned s = 0;
    #pragma unroll
    for (int i = 0; i < 8; ++i) { v[i] = cnt[base + i]; s += v[i]; }
    tt[t] = s;
    __syncthreads();
    for (int d = 1; d < 256; d <<= 1) {
        unsigned y = 0;
        if (t >= d) y = tt[t - d];
        __syncthreads();
        if (t >= d) tt[t] += y;
        __syncthreads();
    }
    unsigned run = bsum[blockIdx.x] + ((t > 0) ? tt[t - 1] : 0u);
    #pragma unroll
    for (int i = 0; i < 8; ++i) { off[base + i] = run; run += v[i]; }
}

// Place atoms into bin-sorted order. Destroys off[] (becomes end pointers).
__global__ void __launch_bounds__(256) place_kernel(const unsigned* __restrict__ vox,
                                                    unsigned* __restrict__ off,
                                                    unsigned* __restrict__ atomIdx) {
    const int atom = blockIdx.x * 256 + threadIdx.x;
    const unsigned bin = vox[atom];
    const unsigned pos = atomicAdd(&off[bin], 1u);
    atomIdx[pos] = atom;
}

// One thread per output cell. W/bias read via wave-uniform scalar loads (SGPR,
// K$-cached) -> matvec is pure v_fmac, no LDS pipe. Empty waves write zeros
// and exit (wave-uniform branch, no divergence cost).
__global__ void __launch_bounds__(256) gather_kernel(const unsigned* __restrict__ cnt,
                                                     const unsigned* __restrict__ off_end,
                                                     const unsigned* __restrict__ atomIdx,
                                                     const float* __restrict__ features,
                                                     const float* __restrict__ W,
                                                     const float* __restrict__ bias,
                                                     float* __restrict__ out) {
    const int b = blockIdx.x >> 7;                 // 128 chunks of 256 cells per batch
    const int spatial = ((blockIdx.x & 127) << 8) + threadIdx.x;
    const unsigned bin = ((unsigned)b << 15) + (unsigned)spatial;
    const unsigned k = cnt[bin];
    float* outb = out + (size_t)b * Ff * G3 + spatial;

    if (!__any((int)k)) {                          // whole wave empty: zero-fill, done
        #pragma unroll
        for (int f = 0; f < Ff; ++f) outb[(size_t)f * G3] = 0.0f;
        return;
    }

    const unsigned start = off_end[bin] - k;
    float acc[Ff];
    #pragma unroll
    for (int j = 0; j < Ff; ++j) acc[j] = 0.0f;
    for (unsigned i = 0; i < k; ++i) {
        const unsigned a = atomIdx[start + i];
        const float4* f4 = reinterpret_cast<const float4*>(features + (size_t)a * Ff);
        #pragma unroll
        for (int q = 0; q < 8; ++q) {
            const float4 v = f4[q];
            acc[4 * q + 0] += v.x; acc[4 * q + 1] += v.y;
            acc[4 * q + 2] += v.z; acc[4 * q + 3] += v.w;
        }
    }

    const float fk = (float)k;
    #pragma unroll
    for (int f = 0; f < Ff; f += 4) {              // 4 independent FMA chains
        float v0 = fk * bias[f + 0];
        float v1 = fk * bias[f + 1];
        float v2 = fk * bias[f + 2];
        float v3 = fk * bias[f + 3];
        #pragma unroll
        for (int j = 0; j < Ff; ++j) {
            const float a = acc[j];
            v0 += W[(f + 0) * Ff + j] * a;         // uniform idx -> s_load, v_fmac v,s,v
            v1 += W[(f + 1) * Ff + j] * a;
            v2 += W[(f + 2) * Ff + j] * a;
            v3 += W[(f + 3) * Ff + j] * a;
        }
        outb[(size_t)(f + 0) * G3] = v0;
        outb[(size_t)(f + 1) * G3] = v1;
        outb[(size_t)(f + 2) * G3] = v2;
        outb[(size_t)(f + 3) * G3] = v3;
    }
}

// ---------- fallback (old atomic path) if ws is too small ----------
__global__ void __launch_bounds__(256) scatter_kernel(const float* __restrict__ coords,
                                                      const float* __restrict__ features,
                                                      const float* __restrict__ W,
                                                      const float* __restrict__ bias,
                                                      const float* __restrict__ centers,
                                                      float* __restrict__ out) {
    __shared__ float Wl[Ff * Ff];
    __shared__ float bl[Ff];
    for (int i = threadIdx.x; i < Ff * Ff; i += 256) Wl[i] = W[i];
    if (threadIdx.x < Ff) bl[threadIdx.x] = bias[threadIdx.x];
    __syncthreads();
    const int atom = blockIdx.x * 256 + threadIdx.x;
    const int b = atom >> 13;
    const float cx = centers[b * 3 + 0];
    const float cy = centers[b * 3 + 1];
    const float cz = centers[b * 3 + 2];
    const float* cp = coords + (size_t)atom * 3;
    const int ix = min(max((int)((cp[0] - cx) + 16.0f), 0), Gg - 1);
    const int iy = min(max((int)((cp[1] - cy) + 16.0f), 0), Gg - 1);
    const int iz = min(max((int)((cp[2] - cz) + 16.0f), 0), Gg - 1);
    const int spatial = ix * (Gg * Gg) + iy * Gg + iz;
    float* outb = out + (size_t)b * Ff * G3 + spatial;
    float ft[Ff];
    const float4* f4 = reinterpret_cast<const float4*>(features + (size_t)atom * Ff);
    #pragma unroll
    for (int q = 0; q < 8; ++q) {
        const float4 v = f4[q];
        ft[4 * q + 0] = v.x; ft[4 * q + 1] = v.y;
        ft[4 * q + 2] = v.z; ft[4 * q + 3] = v.w;
    }
    #pragma unroll 4
    for (int fo = 0; fo < Ff; ++fo) {
        float a2 = bl[fo];
        #pragma unroll
        for (int j = 0; j < Ff; ++j) a2 += Wl[fo * Ff + j] * ft[j];
        atomicAdd(outb + (size_t)fo * G3, a2);
    }
}

extern "C" void kernel_launch(void* const* d_in, const int* in_sizes, int n_in,
                              void* d_out, int out_size, void* d_ws, size_t ws_size,
                              hipStream_t stream) {
    const float* coords   = (const float*)d_in[0];
    const float* features = (const float*)d_in[1];
    const float* W        = (const float*)d_in[2];
    const float* bias     = (const float*)d_in[3];
    float* out = (float*)d_out;

    char* ws = (char*)d_ws;
    float* centers = (float*)(ws + WS_CENTERS);

    if (ws_size < WS_NEED) {
        hipMemsetAsync(d_out, 0, (size_t)out_size * sizeof(float), stream);
        centers_kernel<<<Bb, 256, 0, stream>>>(coords, centers);
        scatter_kernel<<<(NATOM) / 256, 256, 0, stream>>>(coords, features, W, bias, centers, out);
        return;
    }

    unsigned* cnt     = (unsigned*)(ws + WS_CNT);
    unsigned* off     = (unsigned*)(ws + WS_OFF);
    unsigned* vox     = (unsigned*)(ws + WS_VOX);
    unsigned* atomIdx = (unsigned*)(ws + WS_AIDX);
    unsigned* bsum    = (unsigned*)(ws + WS_BSUM);

    zero_cnt_kernel<<<NBINS / 4 / 256, 256, 0, stream>>>((uint4*)cnt);   // 8 MB, coalesced
    centers_kernel<<<Bb, 256, 0, stream>>>(coords, centers);
    binid_kernel<<<NATOM / 256, 256, 0, stream>>>(coords, centers, vox, cnt);
    scan_pass1<<<SCAN_BLK, 256, 0, stream>>>(cnt, bsum);
    scan_pass2<<<1, 256, 0, stream>>>(bsum);
    scan_pass3<<<SCAN_BLK, 256, 0, stream>>>(cnt, bsum, off);
    place_kernel<<<NATOM / 256, 256, 0, stream>>>(vox, off, atomIdx);
    gather_kernel<<<Bb * (G3 / 256), 256, 0, stream>>>(cnt, off, atomIdx, features, W, bias, out);
}

// Round 9
// 145.121 us; speedup vs baseline: 5.6786x; 1.3533x over previous
//
#include <hip/hip_runtime.h>

#define Bb 64
#define Nn 8192
#define Ff 32
#define Gg 32
#define G3 (Gg*Gg*Gg)          // 32768
#define NATOM (Bb*Nn)          // 524288
#define NBINS (Bb*G3)          // 2^21

// ---------------- ws layout ----------------
// [0,1024)        centers (fallback only)
// [1024, +8MB)    meta[NBINS] u32: (end_local<<16)|cnt   (end,cnt <= 8192)
// [+2MB)          atomIdx[NATOM] u32 (global atom id, bin-sorted)
static const size_t WS_CENTERS = 0;
static const size_t WS_META    = 1024;
static const size_t WS_AIDX    = WS_META + (size_t)NBINS * 4;
static const size_t WS_NEED    = WS_AIDX + (size_t)NATOM * 4;

// One block per batch (1024 threads, 8 atoms/thread):
//   fp64 centroid -> two-pass LDS histogram (u32[16384] = 64 KB) -> in-LDS
//   exclusive scan (wave shfl scan; wave totals stashed in high 16 bits of
//   hist[0..15], safe because counts <= 8192 and readers mask &0xFFFF) ->
//   meta writeback -> LDS-atomic placement into atomIdx.
// Replaces: zero(8MB) + binid(524K global atomics) + 3 scan passes + place
// (524K global atomics) = ~32 MB global traffic and 6 launches.
__global__ void __launch_bounds__(1024) fused_sort_kernel(const float* __restrict__ coords,
                                                          unsigned* __restrict__ meta,
                                                          unsigned* __restrict__ atomIdx) {
    __shared__ unsigned long long lds8[8192];      // 64 KB, 8B-aligned
    unsigned* hist = (unsigned*)lds8;              // [16384] bins per pass
    double*   dred = (double*)lds8;                // [1024*3] centroid reduction

    const int b = blockIdx.x;
    const int t = threadIdx.x;
    const int wave = t >> 6, lane = t & 63;

    // ---- load my 8 atoms (n = t + 1024*i) ----
    float ax[8], ay[8], az[8];
    const float* cb = coords + (size_t)b * Nn * 3;
    #pragma unroll
    for (int i = 0; i < 8; ++i) {
        const int n = t + 1024 * i;
        ax[i] = cb[n * 3 + 0]; ay[i] = cb[n * 3 + 1]; az[i] = cb[n * 3 + 2];
    }

    // ---- fp64 centroid ----
    double sx = 0.0, sy = 0.0, sz = 0.0;
    #pragma unroll
    for (int i = 0; i < 8; ++i) { sx += (double)ax[i]; sy += (double)ay[i]; sz += (double)az[i]; }
    dred[t * 3 + 0] = sx; dred[t * 3 + 1] = sy; dred[t * 3 + 2] = sz;
    __syncthreads();
    for (int s = 512; s > 0; s >>= 1) {
        if (t < s) {
            dred[t * 3 + 0] += dred[(t + s) * 3 + 0];
            dred[t * 3 + 1] += dred[(t + s) * 3 + 1];
            dred[t * 3 + 2] += dred[(t + s) * 3 + 2];
        }
        __syncthreads();
    }
    const float cx = (float)(dred[0] * (1.0 / Nn));
    const float cy = (float)(dred[1] * (1.0 / Nn));
    const float cz = (float)(dred[2] * (1.0 / Nn));
    __syncthreads();                               // done with dred; hist reuses LDS

    // ---- voxel bins (15-bit spatial), kept in registers ----
    unsigned bin[8];
    #pragma unroll
    for (int i = 0; i < 8; ++i) {
        const int ix = min(max((int)((ax[i] - cx) + 16.0f), 0), Gg - 1);
        const int iy = min(max((int)((ay[i] - cy) + 16.0f), 0), Gg - 1);
        const int iz = min(max((int)((az[i] - cz) + 16.0f), 0), Gg - 1);
        bin[i] = ((unsigned)ix << 10) | ((unsigned)iy << 5) | (unsigned)iz;
    }

    unsigned passbase = 0;                         // batch-local offset base for pass 1
    for (int pass = 0; pass < 2; ++pass) {
        const unsigned lo = (unsigned)pass << 14;
        // zero histogram
        #pragma unroll
        for (int j = 0; j < 16; ++j) hist[t + 1024 * j] = 0u;
        __syncthreads();
        // count (LDS atomics)
        #pragma unroll
        for (int i = 0; i < 8; ++i)
            if ((bin[i] >> 14) == (unsigned)pass) atomicAdd(&hist[bin[i] & 16383u], 1u);
        __syncthreads();

        // per-thread sum over owned words [t*16, t*16+16)  (mask: stash race benign)
        const int w0 = t * 16;
        unsigned s = 0;
        #pragma unroll
        for (int j = 0; j < 16; ++j) s += hist[w0 + j] & 0xFFFFu;
        // wave-inclusive scan of per-thread sums
        unsigned incl = s;
        #pragma unroll
        for (int d = 1; d < 64; d <<= 1) {
            const unsigned u = __shfl_up(incl, d);
            if (lane >= d) incl += u;
        }
        // stash wave totals in high bits of hist[0..15] (low bits = live counts)
        if (lane == 63) hist[wave] = (hist[wave] & 0xFFFFu) | (incl << 16);
        __syncthreads();
        unsigned wbase = 0, tot = 0;
        #pragma unroll
        for (int w = 0; w < 16; ++w) {
            const unsigned wt = hist[w] >> 16;
            if (w < wave) wbase += wt;
            tot += wt;
        }
        unsigned running = passbase + wbase + (incl - s);   // exclusive, batch-local
        __syncthreads();                            // stash reads done before writeback
        // writeback offsets + meta
        unsigned* mrow = meta + (size_t)b * 32768 + lo;
        #pragma unroll
        for (int j = 0; j < 16; ++j) {
            const unsigned c = hist[w0 + j] & 0xFFFFu;
            hist[w0 + j] = running;                 // start offset for placement
            mrow[w0 + j] = ((running + c) << 16) | c;
            running += c;
        }
        __syncthreads();
        // place (LDS atomic slot grab)
        #pragma unroll
        for (int i = 0; i < 8; ++i)
            if ((bin[i] >> 14) == (unsigned)pass) {
                const unsigned pos = atomicAdd(&hist[bin[i] & 16383u], 1u);
                atomIdx[(size_t)b * Nn + pos] = (unsigned)(b * Nn) + (unsigned)(t + 1024 * i);
            }
        __syncthreads();
        passbase = tot;                             // pass-0 total feeds pass 1
    }
}

// One thread per output cell. meta -> (cnt, end); features gathered via
// atomIdx; W/bias via wave-uniform scalar loads; empty waves zero-fill.
__global__ void __launch_bounds__(256) gather_kernel(const unsigned* __restrict__ meta,
                                                     const unsigned* __restrict__ atomIdx,
                                                     const float* __restrict__ features,
                                                     const float* __restrict__ W,
                                                     const float* __restrict__ bias,
                                                     float* __restrict__ out) {
    const int b = blockIdx.x >> 7;                 // 128 chunks of 256 cells per batch
    const int spatial = ((blockIdx.x & 127) << 8) + threadIdx.x;
    const unsigned m = meta[((size_t)b << 15) + (unsigned)spatial];
    const unsigned k = m & 0xFFFFu;
    float* outb = out + (size_t)b * Ff * G3 + spatial;

    if (!__any((int)k)) {                          // whole wave empty: zero-fill, done
        #pragma unroll
        for (int f = 0; f < Ff; ++f) outb[(size_t)f * G3] = 0.0f;
        return;
    }

    const unsigned start = ((unsigned)b << 13) + (m >> 16) - k;
    float acc[Ff];
    #pragma unroll
    for (int j = 0; j < Ff; ++j) acc[j] = 0.0f;
    for (unsigned i = 0; i < k; ++i) {
        const unsigned a = atomIdx[start + i];
        const float4* f4 = reinterpret_cast<const float4*>(features + (size_t)a * Ff);
        #pragma unroll
        for (int q = 0; q < 8; ++q) {
            const float4 v = f4[q];
            acc[4 * q + 0] += v.x; acc[4 * q + 1] += v.y;
            acc[4 * q + 2] += v.z; acc[4 * q + 3] += v.w;
        }
    }

    const float fk = (float)k;
    #pragma unroll
    for (int f = 0; f < Ff; f += 4) {              // 4 independent FMA chains
        float v0 = fk * bias[f + 0];
        float v1 = fk * bias[f + 1];
        float v2 = fk * bias[f + 2];
        float v3 = fk * bias[f + 3];
        #pragma unroll
        for (int j = 0; j < Ff; ++j) {
            const float a = acc[j];
            v0 += W[(f + 0) * Ff + j] * a;         // uniform idx -> s_load, v_fmac v,s,v
            v1 += W[(f + 1) * Ff + j] * a;
            v2 += W[(f + 2) * Ff + j] * a;
            v3 += W[(f + 3) * Ff + j] * a;
        }
        outb[(size_t)(f + 0) * G3] = v0;
        outb[(size_t)(f + 1) * G3] = v1;
        outb[(size_t)(f + 2) * G3] = v2;
        outb[(size_t)(f + 3) * G3] = v3;
    }
}

// ---------- fallback (atomic path) if ws is too small ----------
__global__ void __launch_bounds__(256) centers_kernel(const float* __restrict__ coords,
                                                      float* __restrict__ centers) {
    const int b = blockIdx.x;
    const int t = threadIdx.x;
    double sx = 0.0, sy = 0.0, sz = 0.0;
    const float* cb = coords + (size_t)b * Nn * 3;
    for (int n = t; n < Nn; n += 256) {
        sx += (double)cb[n * 3 + 0];
        sy += (double)cb[n * 3 + 1];
        sz += (double)cb[n * 3 + 2];
    }
    __shared__ double red[256][3];
    red[t][0] = sx; red[t][1] = sy; red[t][2] = sz;
    __syncthreads();
    for (int s = 128; s > 0; s >>= 1) {
        if (t < s) {
            red[t][0] += red[t + s][0];
            red[t][1] += red[t + s][1];
            red[t][2] += red[t + s][2];
        }
        __syncthreads();
    }
    if (t < 3) centers[b * 3 + t] = (float)(red[0][t] * (1.0 / Nn));
}

__global__ void __launch_bounds__(256) scatter_kernel(const float* __restrict__ coords,
                                                      const float* __restrict__ features,
                                                      const float* __restrict__ W,
                                                      const float* __restrict__ bias,
                                                      const float* __restrict__ centers,
                                                      float* __restrict__ out) {
    __shared__ float Wl[Ff * Ff];
    __shared__ float bl[Ff];
    for (int i = threadIdx.x; i < Ff * Ff; i += 256) Wl[i] = W[i];
    if (threadIdx.x < Ff) bl[threadIdx.x] = bias[threadIdx.x];
    __syncthreads();
    const int atom = blockIdx.x * 256 + threadIdx.x;
    const int b = atom >> 13;
    const float cx = centers[b * 3 + 0];
    const float cy = centers[b * 3 + 1];
    const float cz = centers[b * 3 + 2];
    const float* cp = coords + (size_t)atom * 3;
    const int ix = min(max((int)((cp[0] - cx) + 16.0f), 0), Gg - 1);
    const int iy = min(max((int)((cp[1] - cy) + 16.0f), 0), Gg - 1);
    const int iz = min(max((int)((cp[2] - cz) + 16.0f), 0), Gg - 1);
    const int spatial = ix * (Gg * Gg) + iy * Gg + iz;
    float* outb = out + (size_t)b * Ff * G3 + spatial;
    float ft[Ff];
    const float4* f4 = reinterpret_cast<const float4*>(features + (size_t)atom * Ff);
    #pragma unroll
    for (int q = 0; q < 8; ++q) {
        const float4 v = f4[q];
        ft[4 * q + 0] = v.x; ft[4 * q + 1] = v.y;
        ft[4 * q + 2] = v.z; ft[4 * q + 3] = v.w;
    }
    #pragma unroll 4
    for (int fo = 0; fo < Ff; ++fo) {
        float a2 = bl[fo];
        #pragma unroll
        for (int j = 0; j < Ff; ++j) a2 += Wl[fo * Ff + j] * ft[j];
        atomicAdd(outb + (size_t)fo * G3, a2);
    }
}

extern "C" void kernel_launch(void* const* d_in, const int* in_sizes, int n_in,
                              void* d_out, int out_size, void* d_ws, size_t ws_size,
                              hipStream_t stream) {
    const float* coords   = (const float*)d_in[0];
    const float* features = (const float*)d_in[1];
    const float* W        = (const float*)d_in[2];
    const float* bias     = (const float*)d_in[3];
    float* out = (float*)d_out;

    char* ws = (char*)d_ws;

    if (ws_size < WS_NEED) {
        float* centers = (float*)(ws + WS_CENTERS);
        hipMemsetAsync(d_out, 0, (size_t)out_size * sizeof(float), stream);
        centers_kernel<<<Bb, 256, 0, stream>>>(coords, centers);
        scatter_kernel<<<(NATOM) / 256, 256, 0, stream>>>(coords, features, W, bias, centers, out);
        return;
    }

    unsigned* meta    = (unsigned*)(ws + WS_META);
    unsigned* atomIdx = (unsigned*)(ws + WS_AIDX);

    fused_sort_kernel<<<Bb, 1024, 0, stream>>>(coords, meta, atomIdx);
    gather_kernel<<<Bb * (G3 / 256), 256, 0, stream>>>(meta, atomIdx, features, W, bias, out);
}